// Round 12
// baseline (83.989 us; speedup 1.0000x reference)
//
#include <hip/hip_runtime.h>
#include <hip/hip_bf16.h>

typedef __attribute__((ext_vector_type(4))) float f32x4;
typedef __attribute__((ext_vector_type(8))) short bf16x8;
typedef __attribute__((ext_vector_type(4))) short s16x4;

#define H1S 72  // padded bf16 stride (144 B rows: 16B-aligned)

struct Smem {
    float inp[384];          // base input vector (real actions), f32
    float base[64];          // b1 + hidden-part of layer 1 (no action rows)
    float sub[8][64];        // sub[g][f] = W1 row of agent g's real action
    int   sel[8];            // real-action index per agent
    union {                  // part's last read is barrier-separated from h1's first write
        float part[4][64];
        __align__(16) short h1[128 * H1S];  // h1 in bf16
    } u;
};

template<bool ISF32>
__device__ __forceinline__ float ldin(const void* p, int i) {
    if constexpr (ISF32) return ((const float*)p)[i];
    else return __bfloat162float(((const __hip_bfloat16*)p)[i]);
}

template<bool ISF32>
__device__ __forceinline__ f32x4 ldq(const void* p, int i) {
    if constexpr (ISF32) return *(const f32x4*)((const float*)p + i);
    else {
        const __hip_bfloat16* q = (const __hip_bfloat16*)p + i;
        return (f32x4){__bfloat162float(q[0]), __bfloat162float(q[1]),
                       __bfloat162float(q[2]), __bfloat162float(q[3])};
    }
}

__device__ __forceinline__ short bf16bits(float v) {
    __hip_bfloat16 h = __float2bfloat16(v);
    return *(const short*)&h;
}
__device__ __forceinline__ float bf16val(short s) {
    return __bfloat162float(*(const __hip_bfloat16*)&s);
}

__device__ __forceinline__ bool word_looks_bf16(unsigned int w) {
    const unsigned int lo = w & 0xFFFFu;
    const unsigned int ex = (lo >> 7) & 0xFFu;
    return (ex >= 100u && ex <= 140u) || (lo & 0x7FFFu) == 0u;
}

template<bool ISF32>
__device__ void qtran_body(Smem& sm,
    const void* __restrict__ hidden, const void* __restrict__ actions,
    const void* __restrict__ w1, const void* __restrict__ b1,
    const void* __restrict__ w2, const void* __restrict__ b2,
    const void* __restrict__ w3, const void* __restrict__ b3,
    void* __restrict__ out, int b, int t)
{
    const int lane = t & 63;
    const int wv = t >> 6;
    const int q = lane >> 4;
    const int n = lane & 15;
    const int fq = lane & 15;
    const int rofs = lane >> 4;

    // ---- phase 0: stage input vector (f32x4 loads) ----
    if (t < 64) {
        const int j = t >> 3, k4 = (t & 7) * 4;
        *(f32x4*)&sm.inp[j * 48 + k4] = ldq<ISF32>(hidden, (b * 8 + j) * 32 + k4);
    } else if (t < 96) {
        const int i = t - 64;
        const int j = i >> 2, c4 = (i & 3) * 4;
        *(f32x4*)&sm.inp[j * 48 + 32 + c4] = ldq<ISF32>(actions, (b * 8 + j) * 16 + c4);
    }
    __syncthreads();

    // ---- phase 1a: find each agent's real-action index (one-hot) ----
    if (t < 128) {
        const int g = t >> 4, a = t & 15;
        if (sm.inp[g * 48 + 32 + a] > 0.5f) sm.sel[g] = a;
    }

    // ---- phase 1: hidden-row layer-1 partials; wave wv covers 64 of 256 rows ----
    {
        f32x4 a4 = (f32x4){0.f, 0.f, 0.f, 0.f};
        #pragma unroll 8
        for (int p = 0; p < 16; ++p) {
            const int hr = wv * 64 + p * 4 + rofs;   // hidden-row 0..255
            const int r = (hr >> 5) * 48 + (hr & 31);
            const float xv = sm.inp[r];
            const f32x4 wq = ldq<ISF32>(w1, r * 64 + fq * 4);
            #pragma unroll
            for (int c = 0; c < 4; ++c) a4[c] = fmaf(xv, wq[c], a4[c]);
        }
        #pragma unroll
        for (int c = 0; c < 4; ++c) {
            a4[c] += __shfl_xor(a4[c], 16);
            a4[c] += __shfl_xor(a4[c], 32);
        }
        if (rofs == 0) *(f32x4*)&sm.u.part[wv][fq * 4] = a4;
    }
    __syncthreads();

    // ---- phase 2: sub rows / base, disjoint thread groups ----
    if (t < 128) {
        const int g = t >> 4, f4 = (t & 15) * 4;
        *(f32x4*)&sm.sub[g][f4] =
            ldq<ISF32>(w1, (g * 48 + 32 + sm.sel[g]) * 64 + f4);
    } else if (t < 192) {
        const int f = t - 128;
        sm.base[f] = ldin<ISF32>(b1, f) + sm.u.part[0][f] + sm.u.part[1][f]
                   + sm.u.part[2][f] + sm.u.part[3][f];
    }
    __syncthreads();

    // ---- phase 4: h1 for 128 items -> bf16 LDS ----
    {
        const int itm = t >> 4;                      // 16 items per pass
        const int hfq = t & 15;
        f32x4 S = *(const f32x4*)&sm.sub[0][hfq * 4];
        #pragma unroll
        for (int g = 1; g < 8; ++g) {
            const f32x4 sg = *(const f32x4*)&sm.sub[g][hfq * 4];
            #pragma unroll
            for (int c = 0; c < 4; ++c) S[c] += sg[c];
        }
        f32x4 bs = *(const f32x4*)&sm.base[hfq * 4];
        #pragma unroll
        for (int c = 0; c < 4; ++c) bs[c] += S[c];   // base incl. all real actions
        #pragma unroll
        for (int p = 0; p < 8; ++p) {
            const int item = p * 16 + itm;
            const int g = item >> 4, a = item & 15;
            const f32x4 wq = ldq<ISF32>(w1, (g * 48 + 32 + a) * 64 + hfq * 4);
            const f32x4 sb = *(const f32x4*)&sm.sub[g][hfq * 4];
            s16x4 hi;
            #pragma unroll
            for (int c = 0; c < 4; ++c)
                hi[c] = bf16bits(fmaxf(bs[c] - sb[c] + wq[c], 0.f));
            *(s16x4*)&sm.u.h1[item * H1S + hfq * 4] = hi;
        }
    }
    __syncthreads();

    // ---- phase 5: layer 2; B-frags built per-nt from w2 (small live range) ----
    f32x4 acc[2][4];
    #pragma unroll
    for (int mt = 0; mt < 2; ++mt)
      #pragma unroll
      for (int nt = 0; nt < 4; ++nt)
        acc[mt][nt] = (f32x4){0.f, 0.f, 0.f, 0.f};

    #pragma unroll
    for (int ks = 0; ks < 2; ++ks) {
        bf16x8 ahi[2];
        #pragma unroll
        for (int mt = 0; mt < 2; ++mt) {
            const int item = wv * 32 + mt * 16 + n;  // A[m=lane&15][k=quad*8+j]
            ahi[mt] = *(const bf16x8*)&sm.u.h1[item * H1S + ks * 32 + q * 8];
        }
        #pragma unroll
        for (int nt = 0; nt < 4; ++nt) {
            bf16x8 bhi, blo;
            #pragma unroll
            for (int j = 0; j < 8; ++j) {
                const float v = ldin<ISF32>(w2, (ks * 32 + q * 8 + j) * 64 + nt * 16 + n);
                const short hb = bf16bits(v);
                bhi[j] = hb;
                blo[j] = bf16bits(v - bf16val(hb));
            }
            #pragma unroll
            for (int mt = 0; mt < 2; ++mt) {
                acc[mt][nt] = __builtin_amdgcn_mfma_f32_16x16x32_bf16(
                    ahi[mt], bhi, acc[mt][nt], 0, 0, 0);
                acc[mt][nt] = __builtin_amdgcn_mfma_f32_16x16x32_bf16(
                    ahi[mt], blo, acc[mt][nt], 0, 0, 0);
            }
        }
    }

    // ---- epilogue: h2 = relu(acc + b2); qv = h2 . w3 + b3 ----
    float b2f[4], w3f[4];
    #pragma unroll
    for (int nt = 0; nt < 4; ++nt) {
        b2f[nt] = ldin<ISF32>(b2, nt * 16 + n);
        w3f[nt] = ldin<ISF32>(w3, nt * 16 + n);
    }
    const float b3f = ldin<ISF32>(b3, 0);

    #pragma unroll
    for (int mt = 0; mt < 2; ++mt) {
      #pragma unroll
      for (int r = 0; r < 4; ++r) {
        float p = 0.f;
        #pragma unroll
        for (int nt = 0; nt < 4; ++nt) {
            const float h2 = fmaxf(acc[mt][nt][r] + b2f[nt], 0.f); // D: row=q*4+r, col=n
            p = fmaf(h2, w3f[nt], p);
        }
        p += __shfl_xor(p, 1);
        p += __shfl_xor(p, 2);
        p += __shfl_xor(p, 4);
        p += __shfl_xor(p, 8);
        if (n == mt * 4 + r) {
            const int item = wv * 32 + mt * 16 + q * 4 + r;
            if constexpr (ISF32) ((float*)out)[b * 128 + item] = p + b3f;
            else ((__hip_bfloat16*)out)[b * 128 + item] = __float2bfloat16(p + b3f);
        }
      }
    }
}

__global__ __launch_bounds__(256, 6) void qtran_cf_kernel(
    const void* __restrict__ hidden, const void* __restrict__ actions,
    const void* __restrict__ w1, const void* __restrict__ b1,
    const void* __restrict__ w2, const void* __restrict__ b2,
    const void* __restrict__ w3, const void* __restrict__ b3,
    void* __restrict__ out)
{
    __shared__ Smem sm;
    // dtype vote, lane-parallel
    const unsigned int* hw = (const unsigned int*)hidden;
    const bool pass = word_looks_bf16(hw[threadIdx.x & 31]);
    const unsigned long long m = __ballot(pass);
    const bool isf32 = (__popcll(m) < 32);

    const int b = blockIdx.x;
    const int t = threadIdx.x;
    if (isf32)
        qtran_body<true>(sm, hidden, actions, w1, b1, w2, b2, w3, b3, out, b, t);
    else
        qtran_body<false>(sm, hidden, actions, w1, b1, w2, b2, w3, b3, out, b, t);
}

extern "C" void kernel_launch(void* const* d_in, const int* in_sizes, int n_in,
                              void* d_out, int out_size, void* d_ws, size_t ws_size,
                              hipStream_t stream) {
    // Single launch: no prep kernel, no workspace dependency.
    qtran_cf_kernel<<<2048, 256, 0, stream>>>(
        d_in[0], d_in[1], d_in[2], d_in[3], d_in[4], d_in[5], d_in[6], d_in[7],
        d_out);
}

// Round 13
// 82.826 us; speedup vs baseline: 1.0140x; 1.0140x over previous
//
#include <hip/hip_runtime.h>
#include <hip/hip_bf16.h>

typedef __attribute__((ext_vector_type(4))) float f32x4;
typedef __attribute__((ext_vector_type(8))) short bf16x8;
typedef __attribute__((ext_vector_type(4))) short s16x4;

#define H1S 72  // padded bf16 stride (144 B rows: 16B-aligned)

struct Smem {
    float inpH[256];         // hidden part of input vector (8 agents x 32), f32
    float base[64];          // b1 + hidden-part of layer 1 (no action rows)
    float sub[8][64];        // sub[g][f] = W1 row of agent g's real action
    int   sel[8];            // real-action index per agent
    union {                  // part's last read is barrier-separated from h1's first write
        float part[4][64];
        __align__(16) short h1[128 * H1S];  // h1 in bf16
    } u;
};

template<bool ISF32>
__device__ __forceinline__ float ldin(const void* p, int i) {
    if constexpr (ISF32) return ((const float*)p)[i];
    else return __bfloat162float(((const __hip_bfloat16*)p)[i]);
}

template<bool ISF32>
__device__ __forceinline__ f32x4 ldq(const void* p, int i) {
    if constexpr (ISF32) return *(const f32x4*)((const float*)p + i);
    else {
        const __hip_bfloat16* q = (const __hip_bfloat16*)p + i;
        return (f32x4){__bfloat162float(q[0]), __bfloat162float(q[1]),
                       __bfloat162float(q[2]), __bfloat162float(q[3])};
    }
}

__device__ __forceinline__ short bf16bits(float v) {
    __hip_bfloat16 h = __float2bfloat16(v);
    return *(const short*)&h;
}

__device__ __forceinline__ bool word_looks_bf16(unsigned int w) {
    const unsigned int lo = w & 0xFFFFu;
    const unsigned int ex = (lo >> 7) & 0xFFu;
    return (ex >= 100u && ex <= 140u) || (lo & 0x7FFFu) == 0u;
}

template<bool ISF32>
__device__ void qtran_body(Smem& sm,
    const void* __restrict__ hidden, const void* __restrict__ actions,
    const void* __restrict__ w1, const void* __restrict__ b1,
    const void* __restrict__ w2, const void* __restrict__ b2,
    const void* __restrict__ w3, const void* __restrict__ b3,
    void* __restrict__ out, int b, int t)
{
    const int lane = t & 63;
    const int wv = t >> 6;
    const int q = lane >> 4;
    const int n = lane & 15;
    const int fq = lane & 15;
    const int rofs = lane >> 4;

    // ---- phase 0 (pre-barrier, independent): sel from global + hidden -> LDS ----
    if (t < 128) {
        const int g = t >> 4, a = t & 15;
        const float av = ldin<ISF32>(actions, (b * 8 + g) * 16 + a);
        if (av > 0.5f) sm.sel[g] = a;       // exactly one lane per g wins (one-hot)
    }
    if (t < 64)
        *(f32x4*)&sm.inpH[t * 4] = ldq<ISF32>(hidden, b * 256 + t * 4);
    __syncthreads();

    // ---- phase 1: hidden-row layer-1 partials; wave wv covers 64 of 256 rows ----
    {
        f32x4 a4 = (f32x4){0.f, 0.f, 0.f, 0.f};
        #pragma unroll 8
        for (int p = 0; p < 16; ++p) {
            const int hr = wv * 64 + p * 4 + rofs;   // hidden-row 0..255
            const int r = (hr >> 5) * 48 + (hr & 31);
            const float xv = sm.inpH[hr];
            const f32x4 wq = ldq<ISF32>(w1, r * 64 + fq * 4);
            #pragma unroll
            for (int c = 0; c < 4; ++c) a4[c] = fmaf(xv, wq[c], a4[c]);
        }
        #pragma unroll
        for (int c = 0; c < 4; ++c) {
            a4[c] += __shfl_xor(a4[c], 16);
            a4[c] += __shfl_xor(a4[c], 32);
        }
        if (rofs == 0) *(f32x4*)&sm.u.part[wv][fq * 4] = a4;
    }
    __syncthreads();

    // ---- phase 2: sub rows / base, disjoint thread groups ----
    if (t < 128) {
        const int g = t >> 4, f4 = (t & 15) * 4;
        *(f32x4*)&sm.sub[g][f4] =
            ldq<ISF32>(w1, (g * 48 + 32 + sm.sel[g]) * 64 + f4);
    } else if (t < 192) {
        const int f = t - 128;
        sm.base[f] = ldin<ISF32>(b1, f) + sm.u.part[0][f] + sm.u.part[1][f]
                   + sm.u.part[2][f] + sm.u.part[3][f];
    }
    __syncthreads();

    // ---- phase 3: h1 for 128 items -> bf16 LDS ----
    {
        const int itm = t >> 4;                      // 16 items per pass
        const int hfq = t & 15;
        f32x4 S = *(const f32x4*)&sm.sub[0][hfq * 4];
        #pragma unroll
        for (int g = 1; g < 8; ++g) {
            const f32x4 sg = *(const f32x4*)&sm.sub[g][hfq * 4];
            #pragma unroll
            for (int c = 0; c < 4; ++c) S[c] += sg[c];
        }
        f32x4 bs = *(const f32x4*)&sm.base[hfq * 4];
        #pragma unroll
        for (int c = 0; c < 4; ++c) bs[c] += S[c];   // base incl. all real actions
        #pragma unroll
        for (int p = 0; p < 8; ++p) {
            const int item = p * 16 + itm;
            const int g = item >> 4, a = item & 15;
            const f32x4 wq = ldq<ISF32>(w1, (g * 48 + 32 + a) * 64 + hfq * 4);
            const f32x4 sb = *(const f32x4*)&sm.sub[g][hfq * 4];
            s16x4 hi;
            #pragma unroll
            for (int c = 0; c < 4; ++c)
                hi[c] = bf16bits(fmaxf(bs[c] - sb[c] + wq[c], 0.f));
            *(s16x4*)&sm.u.h1[item * H1S + hfq * 4] = hi;
        }
    }
    __syncthreads();

    // ---- phase 4: layer 2; single-bf16 W2 (precision headroom: 3.7x) ----
    f32x4 acc[2][4];
    #pragma unroll
    for (int mt = 0; mt < 2; ++mt)
      #pragma unroll
      for (int nt = 0; nt < 4; ++nt)
        acc[mt][nt] = (f32x4){0.f, 0.f, 0.f, 0.f};

    #pragma unroll
    for (int ks = 0; ks < 2; ++ks) {
        bf16x8 ahi[2];
        #pragma unroll
        for (int mt = 0; mt < 2; ++mt) {
            const int item = wv * 32 + mt * 16 + n;  // A[m=lane&15][k=quad*8+j]
            ahi[mt] = *(const bf16x8*)&sm.u.h1[item * H1S + ks * 32 + q * 8];
        }
        #pragma unroll
        for (int nt = 0; nt < 4; ++nt) {
            bf16x8 bb;
            #pragma unroll
            for (int j = 0; j < 8; ++j)
                bb[j] = bf16bits(ldin<ISF32>(w2, (ks * 32 + q * 8 + j) * 64 + nt * 16 + n));
            #pragma unroll
            for (int mt = 0; mt < 2; ++mt)
                acc[mt][nt] = __builtin_amdgcn_mfma_f32_16x16x32_bf16(
                    ahi[mt], bb, acc[mt][nt], 0, 0, 0);
        }
    }

    // ---- epilogue: h2 = relu(acc + b2); qv = h2 . w3 + b3 ----
    float b2f[4], w3f[4];
    #pragma unroll
    for (int nt = 0; nt < 4; ++nt) {
        b2f[nt] = ldin<ISF32>(b2, nt * 16 + n);
        w3f[nt] = ldin<ISF32>(w3, nt * 16 + n);
    }
    const float b3f = ldin<ISF32>(b3, 0);

    #pragma unroll
    for (int mt = 0; mt < 2; ++mt) {
      #pragma unroll
      for (int r = 0; r < 4; ++r) {
        float p = 0.f;
        #pragma unroll
        for (int nt = 0; nt < 4; ++nt) {
            const float h2 = fmaxf(acc[mt][nt][r] + b2f[nt], 0.f); // D: row=q*4+r, col=n
            p = fmaf(h2, w3f[nt], p);
        }
        p += __shfl_xor(p, 1);
        p += __shfl_xor(p, 2);
        p += __shfl_xor(p, 4);
        p += __shfl_xor(p, 8);
        if (n == mt * 4 + r) {
            const int item = wv * 32 + mt * 16 + q * 4 + r;
            if constexpr (ISF32) ((float*)out)[b * 128 + item] = p + b3f;
            else ((__hip_bfloat16*)out)[b * 128 + item] = __float2bfloat16(p + b3f);
        }
      }
    }
}

__global__ __launch_bounds__(256, 4) void qtran_cf_kernel(
    const void* __restrict__ hidden, const void* __restrict__ actions,
    const void* __restrict__ w1, const void* __restrict__ b1,
    const void* __restrict__ w2, const void* __restrict__ b2,
    const void* __restrict__ w3, const void* __restrict__ b3,
    void* __restrict__ out)
{
    __shared__ Smem sm;
    // dtype vote, lane-parallel
    const unsigned int* hw = (const unsigned int*)hidden;
    const bool pass = word_looks_bf16(hw[threadIdx.x & 31]);
    const unsigned long long m = __ballot(pass);
    const bool isf32 = (__popcll(m) < 32);

    const int b = blockIdx.x;
    const int t = threadIdx.x;
    if (isf32)
        qtran_body<true>(sm, hidden, actions, w1, b1, w2, b2, w3, b3, out, b, t);
    else
        qtran_body<false>(sm, hidden, actions, w1, b1, w2, b2, w3, b3, out, b, t);
}

extern "C" void kernel_launch(void* const* d_in, const int* in_sizes, int n_in,
                              void* d_out, int out_size, void* d_ws, size_t ws_size,
                              hipStream_t stream) {
    // Single launch: no prep kernel, no workspace dependency.
    qtran_cf_kernel<<<2048, 256, 0, stream>>>(
        d_in[0], d_in[1], d_in[2], d_in[3], d_in[4], d_in[5], d_in[6], d_in[7],
        d_out);
}